// Round 6
// baseline (38.172 us; speedup 1.0000x reference)
//
#include <hip/hip_runtime.h>

#define NC 256   // channels
#define NK 16    // cluster centers

// Native clang vector type (HIP_vector_type float4 rejected by some builtins).
typedef float f32x4 __attribute__((ext_vector_type(4)));

// Bit-exact replica of the reference's per-element assignment for ANY t:
// scan k ascending, strict <  -> first index wins ties (jnp.argmin semantics).
__device__ __forceinline__ float argmin16(float t, const float* cen) {
    float best = 3.4e38f;
    float bc = 0.0f;
#pragma unroll
    for (int k = 0; k < NK; ++k) {
        float d = fabsf(t - cen[k]);
        bool p = d < best;
        best = p ? d : best;
        bc   = p ? cen[k] : bc;
    }
    return bc;
}

// DIAGNOSTIC ROUND: identical streaming body executed TWICE (second pass
// stores identical values -> output unchanged, deterministic). Purpose:
// split dur_us into (real kernel time) + (fixed replay overhead), and push
// our dispatch into the rocprof top-5 to get its first direct counter row.
__global__ __launch_bounds__(256) void lutfq_kernel(
    const f32x4* __restrict__ x,
    const float* __restrict__ scales,
    const float* __restrict__ centers,
    f32x4*       __restrict__ out,
    int n4)
{
    // 512-bucket LUT over u2 = 2t; bucket ub covers u2 in [ub-256, ub-255).
    // Integer centers -> decision midpoints are half-integers = bucket edges,
    // so the assignment is constant on every bucket interior.
    __shared__ float s_lut[512];

    float cen[NK];
#pragma unroll
    for (int k = 0; k < NK; ++k) cen[k] = rintf(centers[k]);  // round-half-to-even

    const int tid = threadIdx.x;

    // Buckets 0 and 510 built at their LEFT edge (t = -128.0 / 127.0): those
    // points are provably not midpoints of distinct integer centers in
    // [-128,127], so clip masses are served exactly with no fallback.
    for (int ub = tid; ub < 512; ub += 256) {
        float t;
        if (ub == 0)        t = -128.0f;
        else if (ub >= 510) t = 127.0f;
        else                t = 0.5f * (float)(ub - 256) + 0.25f;
        s_lut[ub] = argmin16(t, cen);
    }

    // Per-thread channels are grid-stride-invariant (stride % 64 == 0).
    const int c4 = (tid & 63) * 4;
    const f32x4 sv = *reinterpret_cast<const f32x4*>(&scales[c4]);
    float den[4], r256[4], so[4];
#pragma unroll
    for (int j = 0; j < 4; ++j) {
        float s = sv[j];
        den[j]  = s + 1e-8f;        // ref's denominator
        r256[j] = 256.0f / den[j];  // fast-path reciprocal (<=1 ulp on u2)
        so[j]   = s * 0.0078125f;   // s/128, exact
    }
    __syncthreads();

    const int stride = gridDim.x * blockDim.x;
    const int base   = blockIdx.x * blockDim.x + tid;

#pragma unroll 1
    for (int pass = 0; pass < 2; ++pass) {
        for (int i = base; i < n4; i += stride) {
            f32x4 xv = x[i];
            f32x4 r;
#pragma unroll
            for (int j = 0; j < 4; ++j) {
                // u2 = 2 * clip(x/(s+eps)*128, -128, 127) as one mul + clamp.
                float u2 = xv[j] * r256[j];
                u2 = fminf(fmaxf(u2, -256.0f), 254.0f);

                float fl   = floorf(u2);      // exact
                float frac = u2 - fl;
                int   ub   = (int)fl + 256;   // 0..510

                float c = s_lut[ub];

                // Edge band (reciprocal error + ref tie band), minus the
                // provably-safe clamp rails: replay exact ref arithmetic.
                bool band = (frac < 0x1p-12f) | (frac > 1.0f - 0x1p-12f);
                bool rail = (u2 == -256.0f) | (u2 == 254.0f);
                if (band && !rail) {
                    float t = (xv[j] / den[j]) * 128.0f;
                    t = fminf(fmaxf(t, -128.0f), 127.0f);
                    c = argmin16(t, cen);
                }
                r[j] = c * so[j];   // c*(s/128) == (c/128)*s bit-exactly
            }
            out[i] = r;
        }
        // Forbid cross-pass CSE/DCE: compiler must re-load x and re-store out.
        asm volatile("" ::: "memory");
    }
}

extern "C" void kernel_launch(void* const* d_in, const int* in_sizes, int n_in,
                              void* d_out, int out_size, void* d_ws, size_t ws_size,
                              hipStream_t stream) {
    const float* x       = (const float*)d_in[0];
    const float* scales  = (const float*)d_in[1];
    const float* centers = (const float*)d_in[2];
    float* out = (float*)d_out;

    int n4 = out_size / 4;
    int blocks = (n4 + 255) / 256;
    if (blocks > 2048) blocks = 2048;  // 8192 waves = 32/CU, full occupancy

    lutfq_kernel<<<blocks, 256, 0, stream>>>(
        (const f32x4*)x, scales, centers, (f32x4*)out, n4);
}